// Round 1
// baseline (1206.201 us; speedup 1.0000x reference)
//
#include <hip/hip_runtime.h>

#define N_PTS   65536
#define LATENT  128
#define HIDDEN  512
#define OUT_D   64
#define NBUCKET 1024

// ---------------- kernel 1: fused MLP + LSH bucket + segment sums ----------------
__global__ __launch_bounds__(256) void mlp_kernel(
    const float* __restrict__ z, const float* __restrict__ W1,
    const float* __restrict__ b1, const float* __restrict__ W2,
    const float* __restrict__ b2, const float* __restrict__ a,
    const float* __restrict__ lsh_b,
    float* __restrict__ x_out, float* __restrict__ xnorm_out,
    float* __restrict__ sums, float* __restrict__ counts)
{
    __shared__ float zt[16][128];   // 8 KB
    __shared__ float ht[16][512];   // 32 KB (reads are wave-uniform broadcasts -> no pad needed)
    __shared__ float xt[16][64];    // 4 KB
    const int t = threadIdx.x;
    const int row0 = blockIdx.x * 16;

    // load z tile (16x128), coalesced
    for (int i = t; i < 16 * 128; i += 256)
        zt[i >> 7][i & 127] = z[row0 * 128 + i];
    __syncthreads();

    // GEMM1: h = relu(z @ W1 + b1); thread owns cols j0=t, j1=t+256, all 16 rows
    {
        float acc0[16], acc1[16];
#pragma unroll
        for (int r = 0; r < 16; ++r) { acc0[r] = 0.f; acc1[r] = 0.f; }
        const int j0 = t, j1 = t + 256;
        for (int k = 0; k < 128; k += 4) {
            const float w00 = W1[(k + 0) * 512 + j0];
            const float w01 = W1[(k + 1) * 512 + j0];
            const float w02 = W1[(k + 2) * 512 + j0];
            const float w03 = W1[(k + 3) * 512 + j0];
            const float w10 = W1[(k + 0) * 512 + j1];
            const float w11 = W1[(k + 1) * 512 + j1];
            const float w12 = W1[(k + 2) * 512 + j1];
            const float w13 = W1[(k + 3) * 512 + j1];
#pragma unroll
            for (int r = 0; r < 16; ++r) {
                const float4 zv = *reinterpret_cast<const float4*>(&zt[r][k]);
                acc0[r] = fmaf(zv.x, w00, acc0[r]);
                acc0[r] = fmaf(zv.y, w01, acc0[r]);
                acc0[r] = fmaf(zv.z, w02, acc0[r]);
                acc0[r] = fmaf(zv.w, w03, acc0[r]);
                acc1[r] = fmaf(zv.x, w10, acc1[r]);
                acc1[r] = fmaf(zv.y, w11, acc1[r]);
                acc1[r] = fmaf(zv.z, w12, acc1[r]);
                acc1[r] = fmaf(zv.w, w13, acc1[r]);
            }
        }
        const float bb0 = b1[j0], bb1 = b1[j1];
#pragma unroll
        for (int r = 0; r < 16; ++r) {
            ht[r][j0] = fmaxf(acc0[r] + bb0, 0.f);
            ht[r][j1] = fmaxf(acc1[r] + bb1, 0.f);
        }
    }
    __syncthreads();

    // GEMM2: x = h @ W2 + b2; thread owns 2 cols x 2 rows
    {
        const int j0 = t & 31, j1 = j0 + 32;
        const int r0 = (t >> 5) * 2, r1 = r0 + 1;
        float a00 = 0.f, a01 = 0.f, a10 = 0.f, a11 = 0.f;
        for (int k = 0; k < 512; k += 4) {
            const float4 h0 = *reinterpret_cast<const float4*>(&ht[r0][k]);
            const float4 h1 = *reinterpret_cast<const float4*>(&ht[r1][k]);
            const float w00 = W2[(k + 0) * 64 + j0];
            const float w01 = W2[(k + 1) * 64 + j0];
            const float w02 = W2[(k + 2) * 64 + j0];
            const float w03 = W2[(k + 3) * 64 + j0];
            const float w10 = W2[(k + 0) * 64 + j1];
            const float w11 = W2[(k + 1) * 64 + j1];
            const float w12 = W2[(k + 2) * 64 + j1];
            const float w13 = W2[(k + 3) * 64 + j1];
            a00 = fmaf(h0.x, w00, a00); a00 = fmaf(h0.y, w01, a00);
            a00 = fmaf(h0.z, w02, a00); a00 = fmaf(h0.w, w03, a00);
            a01 = fmaf(h0.x, w10, a01); a01 = fmaf(h0.y, w11, a01);
            a01 = fmaf(h0.z, w12, a01); a01 = fmaf(h0.w, w13, a01);
            a10 = fmaf(h1.x, w00, a10); a10 = fmaf(h1.y, w01, a10);
            a10 = fmaf(h1.z, w02, a10); a10 = fmaf(h1.w, w03, a10);
            a11 = fmaf(h1.x, w10, a11); a11 = fmaf(h1.y, w11, a11);
            a11 = fmaf(h1.z, w12, a11); a11 = fmaf(h1.w, w13, a11);
        }
        const float bb0 = b2[j0], bb1 = b2[j1];
        const float x00 = a00 + bb0, x01 = a01 + bb1;
        const float x10 = a10 + bb0, x11 = a11 + bb1;
        xt[r0][j0] = x00; xt[r0][j1] = x01;
        xt[r1][j0] = x10; xt[r1][j1] = x11;
        x_out[(size_t)(row0 + r0) * 64 + j0] = x00;
        x_out[(size_t)(row0 + r0) * 64 + j1] = x01;
        x_out[(size_t)(row0 + r1) * 64 + j0] = x10;
        x_out[(size_t)(row0 + r1) * 64 + j1] = x11;
    }
    __syncthreads();

    // per-row: x.a -> bucket; ||x||^2; atomic segment sums/counts
    {
        const int r = t >> 4;   // 0..15
        const int g = t & 15;   // 0..15 (16 threads per row, within one wave)
        float sa = 0.f, sn = 0.f;
#pragma unroll
        for (int i = 0; i < 4; ++i) {
            const int k = g + 16 * i;
            const float xv = xt[r][k];
            sa = fmaf(xv, a[k], sa);
            sn = fmaf(xv, xv, sn);
        }
#pragma unroll
        for (int off = 8; off >= 1; off >>= 1) {
            sa += __shfl_xor(sa, off, 16);
            sn += __shfl_xor(sn, off, 16);
        }
        const float code = floorf((sa + lsh_b[0]) * 0.25f);   // /4.0 exact
        const int bkt = ((int)code) & (NBUCKET - 1);          // python-mod, pow2
        if (g == 0) {
            xnorm_out[row0 + r] = sn;
            atomicAdd(&counts[bkt], 1.0f);
        }
#pragma unroll
        for (int i = 0; i < 4; ++i) {
            const int k = g + 16 * i;
            atomicAdd(&sums[bkt * 64 + k], xt[r][k]);
        }
    }
}

// ---------------- kernel 2: means = sums / max(counts,1); mnorm ----------------
__global__ __launch_bounds__(64) void means_kernel(
    const float* __restrict__ sums, const float* __restrict__ counts,
    float* __restrict__ means_out, float* __restrict__ mnorm)
{
    const int b = blockIdx.x;
    const int k = threadIdx.x;
    const float c = fmaxf(counts[b], 1.0f);
    const float m = sums[b * 64 + k] / c;
    means_out[b * 64 + k] = m;
    float s = m * m;
#pragma unroll
    for (int off = 32; off >= 1; off >>= 1) s += __shfl_xor(s, off, 64);
    if (k == 0) mnorm[b] = s;
}

// ---------------- kernel 3: q_s via gram trick ----------------
// block = 256 thr (4 waves) covers 16 rows x 1024 buckets.
// wave w owns rows w*4..w*4+3; lane l owns buckets {c*256 + bb*64 + l}.
// means staged in LDS per 256-bucket chunk with 16B-granule XOR swizzle.
__global__ __launch_bounds__(256) void q_kernel(
    const float* __restrict__ x, const float* __restrict__ xnorm,
    const float* __restrict__ means, const float* __restrict__ mnorm,
    float* __restrict__ q_out)
{
    __shared__ float4 mlds4[256 * 16];  // 64 KB
    __shared__ float4 xlds4[16 * 16];   // 4 KB
    const int t = threadIdx.x;
    const int l = t & 63;
    const int w = t >> 6;               // 0..3
    const int row0 = blockIdx.x * 16;
    const float4* x4 = reinterpret_cast<const float4*>(x);
    const float4* m4 = reinterpret_cast<const float4*>(means);

    // x tile: 16 rows x 16 float4, coalesced
    xlds4[t] = x4[(size_t)row0 * 16 + t];

    float xn[4];
#pragma unroll
    for (int r = 0; r < 4; ++r) xn[r] = xnorm[row0 + w * 4 + r];

    float q[4][4][4];                   // [chunk][row][bb] -- fully unrolled indexing only
    float rs[4] = {0.f, 0.f, 0.f, 0.f};
    const int sl = l & 7;

#pragma unroll
    for (int cb = 0; cb < 4; ++cb) {
        __syncthreads();
        // stage chunk: 256 buckets x 16 float4, swizzled by (k4 ^ (b&7))
        for (int i = t; i < 256 * 16; i += 256) {
            const int b = i >> 4, k4 = i & 15;
            mlds4[b * 16 + (k4 ^ (b & 7))] = m4[(size_t)(cb * 256 + b) * 16 + k4];
        }
        __syncthreads();

        float acc[4][4];
#pragma unroll
        for (int r = 0; r < 4; ++r)
#pragma unroll
            for (int bb = 0; bb < 4; ++bb) acc[r][bb] = 0.f;

#pragma unroll 4
        for (int k4 = 0; k4 < 16; ++k4) {
            float4 xv[4];
#pragma unroll
            for (int r = 0; r < 4; ++r) xv[r] = xlds4[(w * 4 + r) * 16 + k4];
            float4 mv[4];
#pragma unroll
            for (int bb = 0; bb < 4; ++bb)
                mv[bb] = mlds4[(bb * 64 + l) * 16 + (k4 ^ sl)];
#pragma unroll
            for (int r = 0; r < 4; ++r)
#pragma unroll
                for (int bb = 0; bb < 4; ++bb) {
                    acc[r][bb] = fmaf(xv[r].x, mv[bb].x, acc[r][bb]);
                    acc[r][bb] = fmaf(xv[r].y, mv[bb].y, acc[r][bb]);
                    acc[r][bb] = fmaf(xv[r].z, mv[bb].z, acc[r][bb]);
                    acc[r][bb] = fmaf(xv[r].w, mv[bb].w, acc[r][bb]);
                }
        }
#pragma unroll
        for (int bb = 0; bb < 4; ++bb) {
            const float mn = mnorm[cb * 256 + bb * 64 + l];
#pragma unroll
            for (int r = 0; r < 4; ++r) {
                const float d2 = fmaxf(xn[r] + mn - 2.f * acc[r][bb], 0.f);
                const float qq = 1.f / (1.f + d2);
                q[cb][r][bb] = qq;
                rs[r] += qq;
            }
        }
    }

    // full-row sum: wave butterfly (wave covers the whole row)
#pragma unroll
    for (int off = 32; off >= 1; off >>= 1)
#pragma unroll
        for (int r = 0; r < 4; ++r) rs[r] += __shfl_xor(rs[r], off, 64);

    float inv[4];
#pragma unroll
    for (int r = 0; r < 4; ++r) inv[r] = 1.f / rs[r];

#pragma unroll
    for (int cb = 0; cb < 4; ++cb)
#pragma unroll
        for (int r = 0; r < 4; ++r) {
            const size_t base = (size_t)(row0 + w * 4 + r) * NBUCKET + cb * 256 + l;
#pragma unroll
            for (int bb = 0; bb < 4; ++bb)
                q_out[base + bb * 64] = q[cb][r][bb] * inv[r];
        }
}

extern "C" void kernel_launch(void* const* d_in, const int* in_sizes, int n_in,
                              void* d_out, int out_size, void* d_ws, size_t ws_size,
                              hipStream_t stream) {
    const float* z    = (const float*)d_in[0];
    const float* W1   = (const float*)d_in[1];
    const float* b1   = (const float*)d_in[2];
    const float* W2   = (const float*)d_in[3];
    const float* b2   = (const float*)d_in[4];
    const float* a    = (const float*)d_in[5];
    const float* lshb = (const float*)d_in[6];

    float* q_out     = (float*)d_out;
    float* means_out = q_out + (size_t)N_PTS * NBUCKET;   // outputs concatenated (q_s, means)

    float* ws     = (float*)d_ws;
    float* x      = ws;                                   // N*64
    float* xnorm  = x + (size_t)N_PTS * 64;               // N
    float* sums   = xnorm + N_PTS;                        // B*64
    float* counts = sums + (size_t)NBUCKET * 64;          // B
    float* mnorm  = counts + NBUCKET;                     // B

    hipMemsetAsync(sums, 0, (size_t)(NBUCKET * 64 + NBUCKET) * sizeof(float), stream);

    mlp_kernel<<<N_PTS / 16, 256, 0, stream>>>(z, W1, b1, W2, b2, a, lshb,
                                               x, xnorm, sums, counts);
    means_kernel<<<NBUCKET, 64, 0, stream>>>(sums, counts, means_out, mnorm);
    q_kernel<<<N_PTS / 16, 256, 0, stream>>>(x, xnorm, means_out, mnorm, q_out);
}